// Round 13
// baseline (2504.673 us; speedup 1.0000x reference)
//
#include <hip/hip_runtime.h>
#include <hip/hip_fp16.h>

#define BB 512
#define TT 512
#define EE 100
#define HH 40
#define GG 120   // 3*HH
#define TC 64    // timesteps per chunk
#define NC 8     // chunks

typedef _Float16 h2_t __attribute__((ext_vector_type(2)));
typedef _Float16 f16x8 __attribute__((ext_vector_type(8)));
typedef float f32x4 __attribute__((ext_vector_type(4)));
#define MFMA16(a, b, c) __builtin_amdgcn_mfma_f32_16x16x32_f16(a, b, c, 0, 0, 0)

__device__ __forceinline__ float fdot2_(h2_t a, h2_t b, float c) {
    return __builtin_amdgcn_fdot2(a, b, c, false);
}
__device__ __forceinline__ h2_t pack2_(float x, float y) {
    h2_t r; r[0] = (_Float16)x; r[1] = (_Float16)y; return r;
}
__device__ __forceinline__ float sigmoid_(float x) {
    return 1.0f / (1.0f + __expf(-x));
}
__device__ __forceinline__ float tanhfast_(float x) {
    float e = __expf(2.0f * x);
    return 1.0f - 2.0f / (e + 1.0f);
}

// rank batches by len desc -> perm[rank] = batch (length-sorted 16-groups)
__global__ __launch_bounds__(BB) void rank_kernel(const int* __restrict__ lens,
                                                  int* __restrict__ perm) {
    __shared__ int L[BB];
    const int i = threadIdx.x;
    L[i] = lens[i];
    __syncthreads();
    const int li = L[i];
    int r = 0;
    for (int jj = 0; jj < BB; ++jj) {
        const int lj = L[jj];
        r += (lj > li) || (lj == li && jj < i);
    }
    perm[r] = i;
}

// Round-13: MFMA-batched scan. One wave = 16 chains (rank-adjacent batches,
// one dir). Per step: gh[16][120] = h[16][40] x Whh^T via 9 N-tiles x 2
// K-chunks of mfma_f32_16x16x32_f16 (Whh B-frags resident, 72 VGPRs).
// Gate math per-lane in C-layout (col=lane&15,row=(lane>>4)*4+reg — m89).
// h round-trip C->A layout via wave-private LDS (12 ds_write_b16 + 2
// ds_read_b128, in-order DS). bhh_r/z folded into GEMM bias; bhh_n is the
// n-tile C-init (n = tanh(gxn+bihn + r*(ghn+bhhn)) — exact PyTorch math).
// Per-row freeze via cndmask; group step range from sorted maxlen.
template<int K, bool GATHER>
__global__ __launch_bounds__(256, 2) void fused_kernel(
    const int cg, const int cs, const int nScan,
    const int* __restrict__ perm,
    const int* __restrict__ text, const float* __restrict__ emb,
    const __half* __restrict__ Xh,
    const float* __restrict__ Wf, const float* __restrict__ bf,
    const float* __restrict__ Wb, const float* __restrict__ bb,
    __half* __restrict__ gxW, const __half* __restrict__ gxR,
    const float* __restrict__ WhhF, const float* __restrict__ bhhF,
    const float* __restrict__ WhhB, const float* __restrict__ bhhB,
    const int* __restrict__ lens,
    __half* __restrict__ out0,
    float* __restrict__ hcar, float* __restrict__ hlast,
    float* __restrict__ sumb, float* __restrict__ maxb)
{
    constexpr int K2 = K / 2;
    __shared__ __align__(16) char smem[26112];  // scan: 4x2KB h_lds; gemm: tiles
    const int tid = threadIdx.x;

    if ((int)blockIdx.x < nScan) {
        // ========== scan: one wave = 16 chains, MFMA-batched ==========
        __builtin_amdgcn_s_setprio(3);
        const int w = tid >> 6, lane = tid & 63;
        const int slot = blockIdx.x * 4 + w;   // 0..63
        const int bg  = slot >> 1;             // 0..31 (16-batch group)
        const int dir = slot & 1;
        const int quad = lane >> 4, col = lane & 15;
        const float* Whh = dir ? WhhB : WhhF;
        const float* bhh = dir ? bhhB : bhhF;
        const int layer = GATHER ? 0 : 1;

        int brl[4], len4[4];
        #pragma unroll
        for (int i = 0; i < 4; ++i) {
            brl[i]  = perm[bg * 16 + quad * 4 + i];
            len4[i] = lens[brl[i]];
        }
        const int maxlen = lens[perm[bg * 16]];   // rank-sorted desc
        const int chunk = dir ? (NC - 1 - cs) : cs;
        const int tbase = chunk * TC;

        int sBeg, sEnd;
        if (dir == 0) { sBeg = 0; sEnd = min(TC, max(0, maxlen - tbase)); }
        else          { sBeg = max(0, tbase + TC - maxlen); sEnd = TC; }

        // B-frags: Bf[tile][kchunk], B[k=(quad*8+e)+32*c][n=col],
        // value = Whh[(g*40+jj)][k], jj=(tile%3)*16+col, g=tile/3
        f16x8 Bf[9][2];
        #pragma unroll
        for (int tt = 0; tt < 9; ++tt) {
            const int g = tt / 3, jj = (tt % 3) * 16 + col;
            #pragma unroll
            for (int c = 0; c < 2; ++c) {
                f16x8 bfv;
                #pragma unroll
                for (int e = 0; e < 8; ++e) {
                    const int k = quad * 8 + e + 32 * c;
                    float v = 0.0f;
                    if (jj < HH && k < HH)
                        v = Whh[(size_t)(g * HH + jj) * HH + k];
                    bfv[e] = (_Float16)v;
                }
                Bf[tt][c] = bfv;
            }
        }
        float bhhn3[3];
        #pragma unroll
        for (int tr = 0; tr < 3; ++tr) {
            const int jj = tr * 16 + col;
            bhhn3[tr] = (jj < HH) ? bhh[2 * HH + jj] : 0.0f;
        }

        // wave-private h_lds[16][64] fp16, pads zero (A chunk1 reads zeros)
        _Float16* hl = (_Float16*)smem + w * 1024;
        {
            float4 z4 = make_float4(0.f, 0.f, 0.f, 0.f);
            ((float4*)hl)[lane * 2]     = z4;
            ((float4*)hl)[lane * 2 + 1] = z4;
        }
        float hreg[12];
        #pragma unroll
        for (int tr = 0; tr < 3; ++tr)
            #pragma unroll
            for (int i = 0; i < 4; ++i) {
                const int j = tr * 16 + col;
                float hv = 0.0f;
                if (cs > 0 && j < HH)
                    hv = hcar[(size_t)(dir * BB + brl[i]) * HH + j];
                hreg[tr * 4 + i] = hv;
                if (j < HH) hl[(quad * 4 + i) * 64 + j] = (_Float16)hv;
            }
        union UA { float4 f; f16x8 h; } ua0, ua1;
        ua0.f = *(const float4*)(hl + col * 64 + quad * 8);
        ua1.f = *(const float4*)(hl + col * 64 + 32 + quad * 8);

        const __half* gp[4];
        #pragma unroll
        for (int i = 0; i < 4; ++i)
            gp[i] = gxR + ((size_t)(dir * BB + brl[i]) * TC) * GG;

        float ps[12], pm[12];
        #pragma unroll
        for (int x = 0; x < 12; ++x) { ps[x] = 0.0f; pm[x] = -3.4e38f; }

        __half q0[36], q1[36];
        #define LOADG(DST, TLOC) {                                             \
            _Pragma("unroll")                                                  \
            for (int i = 0; i < 4; ++i) {                                      \
                const __half* p_ = gp[i] + (TLOC) * GG;                        \
                _Pragma("unroll")                                              \
                for (int tt = 0; tt < 9; ++tt) {                               \
                    const int out_ = (tt / 3) * HH + (tt % 3) * 16 + col;      \
                    DST[tt * 4 + i] = p_[out_];                                \
                }                                                              \
            } }

        #define STEP(CUR, NXT, S) {                                            \
            const int s_ = (S);                                                \
            const int tloc_ = dir ? (TC - 1 - s_) : s_;                        \
            const int t_ = tbase + tloc_;                                      \
            if (s_ + 1 < sEnd) {                                               \
                const int tn_ = dir ? (TC - 2 - s_) : (s_ + 1);                \
                LOADG(NXT, tn_)                                                \
            }                                                                  \
            f32x4 d[9];                                                        \
            _Pragma("unroll")                                                  \
            for (int tt = 0; tt < 9; ++tt) {                                   \
                f32x4 c;                                                       \
                if (tt < 6) {                                                  \
                    _Pragma("unroll")                                          \
                    for (int i = 0; i < 4; ++i) c[i] = (float)CUR[tt*4+i];     \
                } else {                                                       \
                    _Pragma("unroll")                                          \
                    for (int i = 0; i < 4; ++i) c[i] = bhhn3[tt - 6];          \
                }                                                              \
                d[tt] = MFMA16(ua0.h, Bf[tt][0], c);                           \
                d[tt] = MFMA16(ua1.h, Bf[tt][1], d[tt]);                       \
            }                                                                  \
            _Pragma("unroll")                                                  \
            for (int tr = 0; tr < 3; ++tr) {                                   \
                _Pragma("unroll")                                              \
                for (int i = 0; i < 4; ++i) {                                  \
                    const float rr = sigmoid_(d[tr][i]);                       \
                    const float zz = sigmoid_(d[3 + tr][i]);                   \
                    const float npre = (float)CUR[(6+tr)*4+i] + rr*d[6+tr][i]; \
                    const float nn = tanhfast_(npre);                          \
                    const float h0 = hreg[tr * 4 + i];                         \
                    float hn = fmaf(zz, h0 - nn, nn);                          \
                    const bool v = (t_ < len4[i]);                             \
                    hn = v ? hn : h0;                                          \
                    hreg[tr * 4 + i] = hn;                                     \
                    const int j_ = tr * 16 + col;                              \
                    if (j_ < HH) {                                             \
                        hl[(quad * 4 + i) * 64 + j_] = (_Float16)hn;           \
                        if (GATHER) {                                          \
                            const float ov = v ? hn : 0.0f;                    \
                            out0[((size_t)brl[i]*TT + t_)*(2*HH) + dir*HH + j_]\
                                = __float2half(ov);                            \
                        } else if (v) {                                        \
                            ps[tr*4+i] += hn;                                  \
                            pm[tr*4+i] = fmaxf(pm[tr*4+i], hn);                \
                        }                                                      \
                    }                                                          \
                }                                                              \
            }                                                                  \
            ua0.f = *(const float4*)(hl + col * 64 + quad * 8);                \
            ua1.f = *(const float4*)(hl + col * 64 + 32 + quad * 8);           \
        }

        if (sBeg < sEnd) {
            LOADG(q0, dir ? (TC - 1 - sBeg) : sBeg)
            int s = sBeg;
            while (s < sEnd) {
                STEP(q0, q1, s) ++s;
                if (s >= sEnd) break;
                STEP(q1, q0, s) ++s;
            }
        }
        #undef STEP
        #undef LOADG

        #pragma unroll
        for (int tr = 0; tr < 3; ++tr)
            #pragma unroll
            for (int i = 0; i < 4; ++i) {
                const int j = tr * 16 + col;
                if (j >= HH) continue;
                const float hv = hreg[tr * 4 + i];
                hcar[(size_t)(dir * BB + brl[i]) * HH + j] = hv;
                if (cs == NC - 1)
                    hlast[((size_t)(layer*2 + dir) * BB + brl[i]) * HH + j] = hv;
                if (!GATHER) {
                    const size_t pi = (size_t)brl[i] * (2*HH) + dir*HH + j;
                    if (cs == 0) { sumb[pi] = ps[tr*4+i]; maxb[pi] = pm[tr*4+i]; }
                    else { sumb[pi] += ps[tr*4+i];
                           maxb[pi] = fmaxf(maxb[pi], pm[tr*4+i]); }
                }
            }
        return;
    }

    // ================= gemm (fp16 dot2, r9 tile), prio 0 =================
    __builtin_amdgcn_s_setprio(0);
    h2_t* Xs2 = (h2_t*)smem;                     // [K2][64]
    h2_t* Ws2 = (h2_t*)(smem + K2 * 64 * 4);     // [K2][64]
    const int gid = blockIdx.x - nScan;
    const int b   = gid & (BB - 1);
    const int ct  = (gid >> 9) & 1;
    const int dir = gid >> 10;
    const int chunk = dir ? (NC - 1 - cg) : cg;
    const int tbase = chunk * TC;
    if (tbase >= lens[b]) return;   // tile fully past len: gx never read
    const float* W    = dir ? Wb : Wf;
    const float* bias = dir ? bb : bf;
    const float* bhh  = dir ? bhhB : bhhF;
    const int c0 = ct * 64;

    if (GATHER) {
        constexpr int KQ = K / 4;
        for (int idx = tid; idx < 64 * KQ; idx += 256) {
            const int r = idx & 63, q = idx >> 6;
            const int tok = text[b * TT + tbase + r];
            const float4 v = ((const float4*)emb)[(size_t)tok * KQ + q];
            Xs2[(2*q+0)*64 + r] = pack2_(v.x, v.y);
            Xs2[(2*q+1)*64 + r] = pack2_(v.z, v.w);
        }
    } else {
        constexpr int KQ8 = K / 8;
        for (int idx = tid; idx < 64 * KQ8; idx += 256) {
            const int r = idx & 63, q = idx >> 6;
            union { float4 f; h2_t h[4]; } u;
            u.f = ((const float4*)Xh)[((size_t)b * TT + tbase + r) * KQ8 + q];
            #pragma unroll
            for (int i2 = 0; i2 < 4; ++i2)
                Xs2[(4*q + i2)*64 + r] = u.h[i2];
        }
    }
    {
        constexpr int KQ = K / 4;
        for (int idx = tid; idx < 64 * KQ; idx += 256) {
            const int c = idx & 63, q = idx >> 6;
            float4 v = make_float4(0.f,0.f,0.f,0.f);
            if (c0 + c < GG) v = ((const float4*)W)[(size_t)(c0 + c) * KQ + q];
            Ws2[(2*q+0)*64 + c] = pack2_(v.x, v.y);
            Ws2[(2*q+1)*64 + c] = pack2_(v.z, v.w);
        }
    }
    __syncthreads();

    const int tx = tid & 15, ty = tid >> 4;
    float acc[4][4] = {};
    #pragma unroll 2
    for (int k2 = 0; k2 < K2; ++k2) {
        union { float4 f; h2_t h[4]; } xa, wv;
        xa.f = *(const float4*)(Xs2 + k2*64 + (ty << 2));
        wv.f = *(const float4*)(Ws2 + k2*64 + (tx << 2));
        #pragma unroll
        for (int i = 0; i < 4; ++i)
            #pragma unroll
            for (int j2 = 0; j2 < 4; ++j2)
                acc[i][j2] = fdot2_(xa.h[i], wv.h[j2], acc[i][j2]);
    }

    const int c = c0 + (tx << 2);
    if (c < GG) {
        // bias' = bih + (bhh for r,z gates; bhh_n stays in the scan C-init)
        float bv[4];
        #pragma unroll
        for (int j2 = 0; j2 < 4; ++j2) {
            const int cc = c + j2;
            bv[j2] = bias[cc] + (cc < 2*HH ? bhh[cc] : 0.0f);
        }
        const size_t rowB = ((size_t)dir * BB + b) * TC;
        #pragma unroll
        for (int i = 0; i < 4; ++i) {
            const int tloc = (ty << 2) + i;
            union { float2 f; __half2 h[2]; } u;
            u.h[0] = __floats2half2_rn(acc[i][0] + bv[0], acc[i][1] + bv[1]);
            u.h[1] = __floats2half2_rn(acc[i][2] + bv[2], acc[i][3] + bv[3]);
            *(float2*)(gxW + (rowB + tloc) * GG + c) = u.f;
        }
    }
}

// pool_cat = [hb1, hf1, hb0, hf0, avg(80), max(80)] -> fc1(128) -> lrelu -> fc2(1)
__global__ __launch_bounds__(128) void fc_kernel(
    const float* __restrict__ hlast, const float* __restrict__ sumb,
    const float* __restrict__ maxb, const int* __restrict__ lens,
    const float* __restrict__ fc1W, const float* __restrict__ fc1b,
    const float* __restrict__ fc2W, const float* __restrict__ fc2b,
    float* __restrict__ out)
{
    __shared__ float pool[8 * HH];
    __shared__ float red[128];
    const int b = blockIdx.x, tid = threadIdx.x;
    if (tid < HH) {
        pool[tid]        = hlast[(size_t)(3*BB + b) * HH + tid]; // hb1
        pool[HH + tid]   = hlast[(size_t)(2*BB + b) * HH + tid]; // hf1
        pool[2*HH + tid] = hlast[(size_t)(1*BB + b) * HH + tid]; // hb0
        pool[3*HH + tid] = hlast[(size_t)(0*BB + b) * HH + tid]; // hf0
    }
    const float invLen = 1.0f / (float)lens[b];
    if (tid < 2*HH) {
        pool[4*HH + tid] = sumb[(size_t)b * 2*HH + tid] * invLen;
        pool[6*HH + tid] = maxb[(size_t)b * 2*HH + tid];
    }
    __syncthreads();
    float acc = fc1b[tid];
    for (int k = 0; k < 8*HH; ++k)
        acc = fmaf(pool[k], fc1W[(size_t)tid * (8*HH) + k], acc);
    float v = (acc >= 0.0f) ? acc : 0.01f * acc;
    red[tid] = v * fc2W[tid];
    __syncthreads();
    for (int s = 64; s > 0; s >>= 1) {
        if (tid < s) red[tid] += red[tid + s];
        __syncthreads();
    }
    if (tid == 0) out[b] = red[0] + fc2b[0];
}

extern "C" void kernel_launch(void* const* d_in, const int* in_sizes, int n_in,
                              void* d_out, int out_size, void* d_ws, size_t ws_size,
                              hipStream_t stream) {
    const int*   text  = (const int*)d_in[0];
    const int*   lens  = (const int*)d_in[1];
    const float* emb   = (const float*)d_in[2];
    const float* Wih0f = (const float*)d_in[3];
    const float* Whh0f = (const float*)d_in[4];
    const float* bih0f = (const float*)d_in[5];
    const float* bhh0f = (const float*)d_in[6];
    const float* Wih0b = (const float*)d_in[7];
    const float* Whh0b = (const float*)d_in[8];
    const float* bih0b = (const float*)d_in[9];
    const float* bhh0b = (const float*)d_in[10];
    const float* Wih1f = (const float*)d_in[11];
    const float* Whh1f = (const float*)d_in[12];
    const float* bih1f = (const float*)d_in[13];
    const float* bhh1f = (const float*)d_in[14];
    const float* Wih1b = (const float*)d_in[15];
    const float* Whh1b = (const float*)d_in[16];
    const float* bih1b = (const float*)d_in[17];
    const float* bhh1b = (const float*)d_in[18];
    const float* fc1W  = (const float*)d_in[19];
    const float* fc1b  = (const float*)d_in[20];
    const float* fc2W  = (const float*)d_in[21];
    const float* fc2b  = (const float*)d_in[22];
    float* out = (float*)d_out;

    // ws: gx double-buffer fp16 (2 x 15.73MB) | out0 fp16 (41.94MB) | small
    char* p = (char*)d_ws;
    const size_t gxB = (size_t)2 * BB * TC * GG * sizeof(__half);
    __half* gxb0  = (__half*)p;  p += gxB;
    __half* gxb1  = (__half*)p;  p += gxB;
    __half* out0  = (__half*)p;  p += (size_t)BB * TT * 2 * HH * sizeof(__half);
    float*  hcar  = (float*)p;   p += (size_t)2 * BB * HH * sizeof(float);
    float*  hlast = (float*)p;   p += (size_t)4 * BB * HH * sizeof(float);
    float*  sumb  = (float*)p;   p += (size_t)BB * 2 * HH * sizeof(float);
    float*  maxb  = (float*)p;   p += (size_t)BB * 2 * HH * sizeof(float);
    int*    perm  = (int*)p;
    __half* gxb[2] = { gxb0, gxb1 };

    const int NG = BB * 2 * 2;   // 2048 gemm blocks
    const int NS = 16;           // 64 scan waves (16 chains each) / 4

    rank_kernel<<<1, BB, 0, stream>>>(lens, perm);

    // ---- layer 0 ----
    fused_kernel<EE, true><<<NG, 256, 0, stream>>>(0, 0, 0, perm,
        text, emb, nullptr, Wih0f, bih0f, Wih0b, bih0b,
        gxb[0], gxb[0], Whh0f, bhh0f, Whh0b, bhh0b,
        lens, out0, hcar, hlast, sumb, maxb);
    for (int ci = 1; ci < NC; ++ci)
        fused_kernel<EE, true><<<NS + NG, 256, 0, stream>>>(ci, ci - 1, NS, perm,
            text, emb, nullptr, Wih0f, bih0f, Wih0b, bih0b,
            gxb[ci & 1], gxb[(ci - 1) & 1], Whh0f, bhh0f, Whh0b, bhh0b,
            lens, out0, hcar, hlast, sumb, maxb);
    fused_kernel<EE, true><<<NS, 256, 0, stream>>>(0, NC - 1, NS, perm,
        text, emb, nullptr, Wih0f, bih0f, Wih0b, bih0b,
        gxb[0], gxb[(NC - 1) & 1], Whh0f, bhh0f, Whh0b, bhh0b,
        lens, out0, hcar, hlast, sumb, maxb);

    // ---- layer 1 ----
    fused_kernel<2*HH, false><<<NG, 256, 0, stream>>>(0, 0, 0, perm,
        text, emb, out0, Wih1f, bih1f, Wih1b, bih1b,
        gxb[0], gxb[0], Whh1f, bhh1f, Whh1b, bhh1b,
        lens, out0, hcar, hlast, sumb, maxb);
    for (int ci = 1; ci < NC; ++ci)
        fused_kernel<2*HH, false><<<NS + NG, 256, 0, stream>>>(ci, ci - 1, NS, perm,
            text, emb, out0, Wih1f, bih1f, Wih1b, bih1b,
            gxb[ci & 1], gxb[(ci - 1) & 1], Whh1f, bhh1f, Whh1b, bhh1b,
            lens, out0, hcar, hlast, sumb, maxb);
    fused_kernel<2*HH, false><<<NS, 256, 0, stream>>>(0, NC - 1, NS, perm,
        text, emb, out0, Wih1f, bih1f, Wih1b, bih1b,
        gxb[0], gxb[(NC - 1) & 1], Whh1f, bhh1f, Whh1b, bhh1b,
        lens, out0, hcar, hlast, sumb, maxb);

    // ---- head ----
    fc_kernel<<<BB, 128, 0, stream>>>(hlast, sumb, maxb, lens,
        fc1W, fc1b, fc2W, fc2b, out);
}